// Round 3
// baseline (85.712 us; speedup 1.0000x reference)
//
#include <hip/hip_runtime.h>
#include <hip/hip_bf16.h>
#include <math.h>

#define NROWS 4096
#define DDIM  512
#define INV_TAU 1.25f
#define SROW 132   // f32 stride of epilogue LDS chunk rows (bank spread)

typedef __attribute__((ext_vector_type(8))) short short8;
typedef __attribute__((ext_vector_type(4))) float f32x4;

__device__ inline void gload_lds16(const void* g, void* l) {
  __builtin_amdgcn_global_load_lds(
      (const __attribute__((address_space(1))) void*)g,
      (__attribute__((address_space(3))) void*)l, 16, 0, 0);
}

__device__ inline unsigned short f2bf(float f) {
  __hip_bfloat16 h = __float2bfloat16(f);
  return __builtin_bit_cast(unsigned short, h);
}
__device__ inline float bf2f(unsigned short u) {
  return __bfloat162float(__builtin_bit_cast(__hip_bfloat16, u));
}

// ---------------------------------------------------------------------------
// Kernel 1: f32 -> bf16 conversion for v1, v2, W ; zero the nsq accumulators.
// ---------------------------------------------------------------------------
__global__ void convert_kernel(const float* __restrict__ v1,
                               const float* __restrict__ v2,
                               const float* __restrict__ W,
                               unsigned short* __restrict__ v1b,
                               unsigned short* __restrict__ v2b,
                               unsigned short* __restrict__ Wb,
                               float* __restrict__ nsq1,
                               float* __restrict__ nsq2) {
  int idx = blockIdx.x * blockDim.x + threadIdx.x;
  if (idx < NROWS) { nsq1[idx] = 0.f; nsq2[idx] = 0.f; }
  const int TOTV = (NROWS * DDIM) / 4;
  const int TOTW = (DDIM * DDIM) / 4;
  const int total = 2 * TOTV + TOTW;
  const int stride = gridDim.x * blockDim.x;
  for (int i = idx; i < total; i += stride) {
    const float4* src; unsigned short* dst; int j;
    if (i < TOTV)            { src = (const float4*)v1; dst = v1b; j = i; }
    else if (i < 2 * TOTV)   { src = (const float4*)v2; dst = v2b; j = i - TOTV; }
    else                     { src = (const float4*)W;  dst = Wb;  j = i - 2 * TOTV; }
    float4 x = src[j];
    ushort4 o;
    o.x = f2bf(x.x); o.y = f2bf(x.y); o.z = f2bf(x.z); o.w = f2bf(x.w);
    *(ushort4*)&dst[j * 4] = o;
  }
}

// ---------------------------------------------------------------------------
// Kernel 2: projection GEMM  z = elu(v @ W^T + b), bf16 out, + row sum(z^2).
// Single-buffered MM core (kernel is ~2 us total; not the bottleneck).
// grid: (512/128, 4096/128, 2)   block: 256
// ---------------------------------------------------------------------------
__global__ __launch_bounds__(256) void proj_kernel(
    const unsigned short* __restrict__ v1b, const unsigned short* __restrict__ v2b,
    const unsigned short* __restrict__ Wb,  const float* __restrict__ bias,
    unsigned short* __restrict__ z1b, unsigned short* __restrict__ z2b,
    float* __restrict__ nsq1, float* __restrict__ nsq2) {
  __shared__ __align__(16) unsigned short As[128 * 32];
  __shared__ __align__(16) unsigned short Bs[128 * 32];
  const int tid = threadIdx.x;
  const int wid = tid >> 6, lane = tid & 63;
  const int wm = wid >> 1, wn = wid & 1;
  const int l15 = lane & 15, l4 = lane >> 4;

  const int zsel = blockIdx.z;
  const unsigned short* Ag = (zsel ? v2b : v1b) + (size_t)blockIdx.y * 128 * DDIM;
  const unsigned short* Bg = Wb + (size_t)blockIdx.x * 128 * DDIM;
  unsigned short* Z = (zsel ? z2b : z1b);
  float* nsq = (zsel ? nsq2 : nsq1);

  f32x4 acc[4][4];
#pragma unroll
  for (int m = 0; m < 4; ++m)
#pragma unroll
    for (int n = 0; n < 4; ++n) acc[m][n] = (f32x4){0.f, 0.f, 0.f, 0.f};

  for (int kt = 0; kt < DDIM; kt += 32) {
#pragma unroll
    for (int i = 0; i < 2; ++i) {
      int off = i * 4096 + tid * 16;
      int row = off >> 6;
      int kb  = off & 63;
      gload_lds16((const char*)(Ag + row * DDIM + kt) + kb,
                  (char*)As + i * 4096 + wid * 1024);
      gload_lds16((const char*)(Bg + row * DDIM + kt) + kb,
                  (char*)Bs + i * 4096 + wid * 1024);
    }
    asm volatile("s_waitcnt vmcnt(0)" ::: "memory");
    __syncthreads();
    short8 av[4], bv[4];
#pragma unroll
    for (int m = 0; m < 4; ++m)
      av[m] = *(const short8*)&As[(wm * 64 + m * 16 + l15) * 32 + l4 * 8];
#pragma unroll
    for (int n = 0; n < 4; ++n)
      bv[n] = *(const short8*)&Bs[(wn * 64 + n * 16 + l15) * 32 + l4 * 8];
#pragma unroll
    for (int m = 0; m < 4; ++m)
#pragma unroll
      for (int n = 0; n < 4; ++n)
        acc[m][n] = __builtin_amdgcn_mfma_f32_16x16x32_bf16(
            av[m], bv[n], acc[m][n], 0, 0, 0);
    __syncthreads();
  }

  const int rowBase = blockIdx.y * 128 + wm * 64;
  const int colBase = blockIdx.x * 128 + wn * 64;
  float bcol[4];
#pragma unroll
  for (int n = 0; n < 4; ++n) bcol[n] = bias[colBase + n * 16 + l15];
#pragma unroll
  for (int m = 0; m < 4; ++m) {
#pragma unroll
    for (int reg = 0; reg < 4; ++reg) {
      int gRow = rowBase + m * 16 + l4 * 4 + reg;
      float rs = 0.f;
#pragma unroll
      for (int n = 0; n < 4; ++n) {
        int gCol = colBase + n * 16 + l15;
        float y = acc[m][n][reg] + bcol[n];
        float zv = (y > 0.f) ? y : expm1f(y);
        unsigned short zb = f2bf(zv);
        Z[(size_t)gRow * DDIM + gCol] = zb;
        float zf = bf2f(zb);
        rs += zf * zf;
      }
      rs += __shfl_xor(rs, 1, 64);
      rs += __shfl_xor(rs, 2, 64);
      rs += __shfl_xor(rs, 4, 64);
      rs += __shfl_xor(rs, 8, 64);
      if (l15 == 0) atomicAdd(&nsq[gRow], rs);
    }
  }
}

// ---------------------------------------------------------------------------
// Kernel 3: dots = z1 @ z2^T with fused exp/cosine/pos-neg-weighted reduction.
// 2-phase double-buffered GEMM staging + pipelined epilogue + XCD swizzle.
// grid: 1024 linear  block: 256.
// ---------------------------------------------------------------------------
__global__ __launch_bounds__(256) void dots_kernel(
    const unsigned short* __restrict__ z1b, const unsigned short* __restrict__ z2b,
    const float* __restrict__ nsq1, const float* __restrict__ nsq2,
    const float* __restrict__ pos, const float* __restrict__ neg,
    double* __restrict__ partials) {
  // two 16KB staging buffers (each: A tile 8KB | B tile 8KB); epilogue reuses.
  __shared__ __align__(16) char smem[2][16384];
  float* sCh = (float*)smem;   // 32x SROW f32 = 16.9 KB < 32 KB

  const int tid = threadIdx.x;
  const int wid = tid >> 6, lane = tid & 63;
  const int wm = wid >> 1, wn = wid & 1;
  const int l15 = lane & 15, l4 = lane >> 4;

  // bijective XCD swizzle: 1024 blocks, XCD = bid%8 gets contiguous tile range
  const int bid = blockIdx.x;
  const int swz = (bid & 7) * 128 + (bid >> 3);
  const int by = swz >> 5, bx = swz & 31;

  const unsigned short* Ag = z1b + (size_t)by * 128 * DDIM;
  const unsigned short* Bg = z2b + (size_t)bx * 128 * DDIM;

  f32x4 acc[4][4];
#pragma unroll
  for (int m = 0; m < 4; ++m)
#pragma unroll
    for (int n = 0; n < 4; ++n) acc[m][n] = (f32x4){0.f, 0.f, 0.f, 0.f};

#define STAGE(buf, kt)                                                         \
  {                                                                            \
    _Pragma("unroll")                                                          \
    for (int i = 0; i < 2; ++i) {                                              \
      int off = i * 4096 + tid * 16;                                           \
      int row = off >> 6;                                                      \
      int kb  = off & 63;                                                      \
      gload_lds16((const char*)(Ag + row * DDIM + (kt)) + kb,                  \
                  smem[buf] + i * 4096 + wid * 1024);                          \
      gload_lds16((const char*)(Bg + row * DDIM + (kt)) + kb,                  \
                  smem[buf] + 8192 + i * 4096 + wid * 1024);                   \
    }                                                                          \
  }

  // prologue
  STAGE(0, 0);
  asm volatile("s_waitcnt vmcnt(0)" ::: "memory");
  __syncthreads();

#pragma unroll
  for (int t = 0; t < 16; ++t) {
    const int cur = t & 1;
    if (t < 15) STAGE(cur ^ 1, (t + 1) * 32);   // prefetch next tile
    const unsigned short* As = (const unsigned short*)smem[cur];
    const unsigned short* Bs = (const unsigned short*)(smem[cur] + 8192);
    short8 av[4], bv[4];
#pragma unroll
    for (int m = 0; m < 4; ++m)
      av[m] = *(const short8*)&As[(wm * 64 + m * 16 + l15) * 32 + l4 * 8];
#pragma unroll
    for (int n = 0; n < 4; ++n)
      bv[n] = *(const short8*)&Bs[(wn * 64 + n * 16 + l15) * 32 + l4 * 8];
#pragma unroll
    for (int m = 0; m < 4; ++m)
#pragma unroll
      for (int n = 0; n < 4; ++n)
        acc[m][n] = __builtin_amdgcn_mfma_f32_16x16x32_bf16(
            av[m], bv[n], acc[m][n], 0, 0, 0);
    asm volatile("s_waitcnt vmcnt(0)" ::: "memory");  // next tile landed
    __syncthreads();
  }
#undef STAGE

  const int blockRow = by * 128;
  const int blockCol = bx * 128;
  const int rowBase = blockRow + wm * 64;
  const int colBase = blockCol + wn * 64;

  // read-phase mapping: thread t handles chunk row (t>>3), 16 cols at (t&7)*16
  const int lr = tid >> 3;
  const int lcBase = (tid & 7) * 16;
  const int gRowRbase = blockRow + (lr >> 4) * 64 + (lr & 15);
  const int lrW = wm * 16 + l4 * 4;        // + reg
  const int lcW = wn * 64 + l15;           // + n*16

  // issue chunk-0 pos/neg loads first (latency hides under rsqrt/exp below)
  float4 pv[2][4], gv[2][4];
  {
    const float* pr = pos + (size_t)gRowRbase * NROWS + blockCol + lcBase;
    const float* gr = neg + (size_t)gRowRbase * NROWS + blockCol + lcBase;
#pragma unroll
    for (int i = 0; i < 4; ++i) {
      pv[0][i] = *(const float4*)(pr + 4 * i);
      gv[0][i] = *(const float4*)(gr + 4 * i);
    }
  }

  // hoisted inverse norms
  float rs2[4], rs1[4][4];
#pragma unroll
  for (int n = 0; n < 4; ++n) rs2[n] = rsqrtf(nsq2[colBase + n * 16 + l15]);
#pragma unroll
  for (int m = 0; m < 4; ++m)
#pragma unroll
    for (int reg = 0; reg < 4; ++reg)
      rs1[m][reg] = rsqrtf(nsq1[rowBase + m * 16 + l4 * 4 + reg]);

  float sumP = 0.f, sumT = 0.f;
#pragma unroll
  for (int m = 0; m < 4; ++m) {
    const int c = m & 1, o = c ^ 1;
    // exp + scatter into LDS chunk
#pragma unroll
    for (int reg = 0; reg < 4; ++reg) {
#pragma unroll
      for (int n = 0; n < 4; ++n) {
        float s = __expf(acc[m][n][reg] * (rs1[m][reg] * rs2[n]) * INV_TAU);
        sCh[(lrW + reg) * SROW + lcW + n * 16] = s;
      }
    }
    // issue next chunk's pos/neg loads before the barrier (stay in flight)
    if (m < 3) {
      const float* pr = pos + (size_t)(gRowRbase + (m + 1) * 16) * NROWS + blockCol + lcBase;
      const float* gr = neg + (size_t)(gRowRbase + (m + 1) * 16) * NROWS + blockCol + lcBase;
#pragma unroll
      for (int i = 0; i < 4; ++i) {
        pv[o][i] = *(const float4*)(pr + 4 * i);
        gv[o][i] = *(const float4*)(gr + 4 * i);
      }
    }
    __syncthreads();
    // coalesced combine: s (LDS, linear) * pos/neg (regs)
#pragma unroll
    for (int i = 0; i < 4; ++i) {
      float4 s4 = *(const float4*)&sCh[lr * SROW + lcBase + 4 * i];
      sumP += s4.x * pv[c][i].x + s4.y * pv[c][i].y + s4.z * pv[c][i].z + s4.w * pv[c][i].w;
      sumT += s4.x * (pv[c][i].x + gv[c][i].x) + s4.y * (pv[c][i].y + gv[c][i].y) +
              s4.z * (pv[c][i].z + gv[c][i].z) + s4.w * (pv[c][i].w + gv[c][i].w);
    }
    __syncthreads();
  }

#pragma unroll
  for (int sft = 1; sft < 64; sft <<= 1) {
    sumP += __shfl_xor(sumP, sft, 64);
    sumT += __shfl_xor(sumT, sft, 64);
  }
  __shared__ float redP[4], redT[4];
  if (lane == 0) { redP[wid] = sumP; redT[wid] = sumT; }
  __syncthreads();
  if (tid == 0) {
    double tp = (double)redP[0] + redP[1] + redP[2] + redP[3];
    double tt = (double)redT[0] + redT[1] + redT[2] + redT[3];
    partials[2 * bid]     = tp;
    partials[2 * bid + 1] = tt;
  }
}

// ---------------------------------------------------------------------------
// Kernel 4: final reduce of 1024 partial pairs -> -log(sumP / sumT)
// ---------------------------------------------------------------------------
__global__ void finalize_kernel(const double* __restrict__ partials,
                                float* __restrict__ out) {
  __shared__ double sp[256], st[256];
  int t = threadIdx.x;
  double a = 0.0, b = 0.0;
  for (int i = t; i < 1024; i += 256) {
    a += partials[2 * i];
    b += partials[2 * i + 1];
  }
  sp[t] = a; st[t] = b;
  __syncthreads();
  for (int s = 128; s > 0; s >>= 1) {
    if (t < s) { sp[t] += sp[t + s]; st[t] += st[t + s]; }
    __syncthreads();
  }
  if (t == 0) out[0] = (float)(log(st[0]) - log(sp[0]));
}

// ---------------------------------------------------------------------------
extern "C" void kernel_launch(void* const* d_in, const int* in_sizes, int n_in,
                              void* d_out, int out_size, void* d_ws, size_t ws_size,
                              hipStream_t stream) {
  (void)in_sizes; (void)n_in; (void)out_size; (void)ws_size;
  const float* v1   = (const float*)d_in[0];
  const float* v2   = (const float*)d_in[1];
  const float* pos  = (const float*)d_in[2];
  const float* neg  = (const float*)d_in[3];
  const float* W    = (const float*)d_in[4];
  const float* bias = (const float*)d_in[5];

  char* ws = (char*)d_ws;
  unsigned short* z1b = (unsigned short*)(ws + 0);         // 4 MiB
  unsigned short* z2b = (unsigned short*)(ws + 4194304);   // 4 MiB
  unsigned short* v1b = (unsigned short*)(ws + 8388608);   // 4 MiB
  unsigned short* v2b = (unsigned short*)(ws + 12582912);  // 4 MiB
  unsigned short* Wb  = (unsigned short*)(ws + 16777216);  // 512 KiB
  float* nsq1         = (float*)(ws + 17301504);           // 16 KiB
  float* nsq2         = (float*)(ws + 17317888);           // 16 KiB
  double* partials    = (double*)(ws + 17334272);          // 16 KiB
  float* out = (float*)d_out;

  hipLaunchKernelGGL(convert_kernel, dim3(1024), dim3(256), 0, stream,
                     v1, v2, W, v1b, v2b, Wb, nsq1, nsq2);
  hipLaunchKernelGGL(proj_kernel, dim3(DDIM / 128, NROWS / 128, 2), dim3(256), 0, stream,
                     v1b, v2b, Wb, bias, z1b, z2b, nsq1, nsq2);
  hipLaunchKernelGGL(dots_kernel, dim3(1024), dim3(256), 0, stream,
                     z1b, z2b, nsq1, nsq2, pos, neg, partials);
  hipLaunchKernelGGL(finalize_kernel, dim3(1), dim3(256), 0, stream,
                     partials, out);
}

// Round 4
// 75.272 us; speedup vs baseline: 1.1387x; 1.1387x over previous
//
#include <hip/hip_runtime.h>
#include <hip/hip_bf16.h>
#include <math.h>

#define NROWS 4096
#define DDIM  512
#define INV_TAU 1.25f
#define SROW 132   // f32 stride of epilogue LDS chunk rows (bank spread)

typedef __attribute__((ext_vector_type(8))) short short8;
typedef __attribute__((ext_vector_type(4))) float f32x4;

__device__ inline void gload_lds16(const void* g, void* l) {
  __builtin_amdgcn_global_load_lds(
      (const __attribute__((address_space(1))) void*)g,
      (__attribute__((address_space(3))) void*)l, 16, 0, 0);
}

__device__ inline unsigned short f2bf(float f) {
  __hip_bfloat16 h = __float2bfloat16(f);
  return __builtin_bit_cast(unsigned short, h);
}
__device__ inline float bf2f(unsigned short u) {
  return __bfloat162float(__builtin_bit_cast(__hip_bfloat16, u));
}

// ---------------------------------------------------------------------------
// Kernel 1: f32 -> bf16 conversion for v1, v2, W ; zero the nsq accumulators.
// ---------------------------------------------------------------------------
__global__ void convert_kernel(const float* __restrict__ v1,
                               const float* __restrict__ v2,
                               const float* __restrict__ W,
                               unsigned short* __restrict__ v1b,
                               unsigned short* __restrict__ v2b,
                               unsigned short* __restrict__ Wb,
                               float* __restrict__ nsq1,
                               float* __restrict__ nsq2) {
  int idx = blockIdx.x * blockDim.x + threadIdx.x;
  if (idx < NROWS) { nsq1[idx] = 0.f; nsq2[idx] = 0.f; }
  const int TOTV = (NROWS * DDIM) / 4;
  const int TOTW = (DDIM * DDIM) / 4;
  const int total = 2 * TOTV + TOTW;
  const int stride = gridDim.x * blockDim.x;
  for (int i = idx; i < total; i += stride) {
    const float4* src; unsigned short* dst; int j;
    if (i < TOTV)            { src = (const float4*)v1; dst = v1b; j = i; }
    else if (i < 2 * TOTV)   { src = (const float4*)v2; dst = v2b; j = i - TOTV; }
    else                     { src = (const float4*)W;  dst = Wb;  j = i - 2 * TOTV; }
    float4 x = src[j];
    ushort4 o;
    o.x = f2bf(x.x); o.y = f2bf(x.y); o.z = f2bf(x.z); o.w = f2bf(x.w);
    *(ushort4*)&dst[j * 4] = o;
  }
}

// ---------------------------------------------------------------------------
// Kernel 2: projection GEMM  z = elu(v @ W^T + b), bf16 out, + row sum(z^2).
// grid: (512/128, 4096/128, 2)   block: 256
// ---------------------------------------------------------------------------
__global__ __launch_bounds__(256) void proj_kernel(
    const unsigned short* __restrict__ v1b, const unsigned short* __restrict__ v2b,
    const unsigned short* __restrict__ Wb,  const float* __restrict__ bias,
    unsigned short* __restrict__ z1b, unsigned short* __restrict__ z2b,
    float* __restrict__ nsq1, float* __restrict__ nsq2) {
  __shared__ __align__(16) unsigned short As[128 * 32];
  __shared__ __align__(16) unsigned short Bs[128 * 32];
  const int tid = threadIdx.x;
  const int wid = tid >> 6, lane = tid & 63;
  const int wm = wid >> 1, wn = wid & 1;
  const int l15 = lane & 15, l4 = lane >> 4;

  const int zsel = blockIdx.z;
  const unsigned short* Ag = (zsel ? v2b : v1b) + (size_t)blockIdx.y * 128 * DDIM;
  const unsigned short* Bg = Wb + (size_t)blockIdx.x * 128 * DDIM;
  unsigned short* Z = (zsel ? z2b : z1b);
  float* nsq = (zsel ? nsq2 : nsq1);

  f32x4 acc[4][4];
#pragma unroll
  for (int m = 0; m < 4; ++m)
#pragma unroll
    for (int n = 0; n < 4; ++n) acc[m][n] = (f32x4){0.f, 0.f, 0.f, 0.f};

  for (int kt = 0; kt < DDIM; kt += 32) {
#pragma unroll
    for (int i = 0; i < 2; ++i) {
      int off = i * 4096 + tid * 16;
      int row = off >> 6;
      int kb  = off & 63;
      gload_lds16((const char*)(Ag + row * DDIM + kt) + kb,
                  (char*)As + i * 4096 + wid * 1024);
      gload_lds16((const char*)(Bg + row * DDIM + kt) + kb,
                  (char*)Bs + i * 4096 + wid * 1024);
    }
    asm volatile("s_waitcnt vmcnt(0)" ::: "memory");
    __syncthreads();
    short8 av[4], bv[4];
#pragma unroll
    for (int m = 0; m < 4; ++m)
      av[m] = *(const short8*)&As[(wm * 64 + m * 16 + l15) * 32 + l4 * 8];
#pragma unroll
    for (int n = 0; n < 4; ++n)
      bv[n] = *(const short8*)&Bs[(wn * 64 + n * 16 + l15) * 32 + l4 * 8];
#pragma unroll
    for (int m = 0; m < 4; ++m)
#pragma unroll
      for (int n = 0; n < 4; ++n)
        acc[m][n] = __builtin_amdgcn_mfma_f32_16x16x32_bf16(
            av[m], bv[n], acc[m][n], 0, 0, 0);
    __syncthreads();
  }

  const int rowBase = blockIdx.y * 128 + wm * 64;
  const int colBase = blockIdx.x * 128 + wn * 64;
  float bcol[4];
#pragma unroll
  for (int n = 0; n < 4; ++n) bcol[n] = bias[colBase + n * 16 + l15];
#pragma unroll
  for (int m = 0; m < 4; ++m) {
#pragma unroll
    for (int reg = 0; reg < 4; ++reg) {
      int gRow = rowBase + m * 16 + l4 * 4 + reg;
      float rs = 0.f;
#pragma unroll
      for (int n = 0; n < 4; ++n) {
        int gCol = colBase + n * 16 + l15;
        float y = acc[m][n][reg] + bcol[n];
        float zv = (y > 0.f) ? y : expm1f(y);
        unsigned short zb = f2bf(zv);
        Z[(size_t)gRow * DDIM + gCol] = zb;
        float zf = bf2f(zb);
        rs += zf * zf;
      }
      rs += __shfl_xor(rs, 1, 64);
      rs += __shfl_xor(rs, 2, 64);
      rs += __shfl_xor(rs, 4, 64);
      rs += __shfl_xor(rs, 8, 64);
      if (l15 == 0) atomicAdd(&nsq[gRow], rs);
    }
  }
}

// ---------------------------------------------------------------------------
// Kernel 3: dots = z1 @ z2^T fused epilogue.  Counted-vmcnt 2-buffer pipeline:
// raw s_barrier (NO __syncthreads in K-loop -> no vmcnt(0) drain), stage tile
// t+2 after compute barrier, vmcnt(4) keeps tile t+1 in flight across barriers.
// grid: 1024 linear  block: 256.
// ---------------------------------------------------------------------------
__global__ __launch_bounds__(256, 4) void dots_kernel(
    const unsigned short* __restrict__ z1b, const unsigned short* __restrict__ z2b,
    const float* __restrict__ nsq1, const float* __restrict__ nsq2,
    const float* __restrict__ pos, const float* __restrict__ neg,
    double* __restrict__ partials) {
  // two 16KB staging buffers (each: A 8KB | B 8KB); epilogue reuses as sCh.
  __shared__ __align__(16) char smem[2][16384];
  float* sCh = (float*)smem;   // 32 x SROW f32 = 16.9 KB

  const int tid = threadIdx.x;
  const int wid = tid >> 6, lane = tid & 63;
  const int wm = wid >> 1, wn = wid & 1;
  const int l15 = lane & 15, l4 = lane >> 4;

  const int bid = blockIdx.x;
  const int by = bid >> 5, bx = bid & 31;   // linear order (L3-friendly)

  const unsigned short* Ag = z1b + (size_t)by * 128 * DDIM;
  const unsigned short* Bg = z2b + (size_t)bx * 128 * DDIM;

  f32x4 acc[4][4];
#pragma unroll
  for (int m = 0; m < 4; ++m)
#pragma unroll
    for (int n = 0; n < 4; ++n) acc[m][n] = (f32x4){0.f, 0.f, 0.f, 0.f};

  // stage K-tile t (k = t*32) into smem[buf]; 4 global_load_lds per thread
#define STAGE(buf, t)                                                          \
  {                                                                            \
    _Pragma("unroll")                                                          \
    for (int i = 0; i < 2; ++i) {                                              \
      int off = i * 4096 + tid * 16;                                           \
      int row = off >> 6;                                                      \
      int kb  = off & 63;                                                      \
      gload_lds16((const char*)Ag + row * 1024 + (t) * 64 + kb,                \
                  smem[buf] + i * 4096 + wid * 1024);                          \
      gload_lds16((const char*)Bg + row * 1024 + (t) * 64 + kb,                \
                  smem[buf] + 8192 + i * 4096 + wid * 1024);                   \
    }                                                                          \
  }

  // prologue: tiles 0 and 1 in flight (8 outstanding loads)
  STAGE(0, 0);
  STAGE(1, 1);

#pragma unroll
  for (int t = 0; t < 16; ++t) {
    // wait tile t (oldest 4 loads); tile t+1's 4 stay in flight
    if (t < 15) asm volatile("s_waitcnt vmcnt(4)" ::: "memory");
    else        asm volatile("s_waitcnt vmcnt(0)" ::: "memory");
    __builtin_amdgcn_s_barrier();      // raw: no implicit vmcnt drain
    const unsigned short* As = (const unsigned short*)smem[t & 1];
    const unsigned short* Bs = (const unsigned short*)(smem[t & 1] + 8192);
    short8 av[4], bv[4];
#pragma unroll
    for (int m = 0; m < 4; ++m)
      av[m] = *(const short8*)&As[(wm * 64 + m * 16 + l15) * 32 + l4 * 8];
#pragma unroll
    for (int n = 0; n < 4; ++n)
      bv[n] = *(const short8*)&Bs[(wn * 64 + n * 16 + l15) * 32 + l4 * 8];
    __builtin_amdgcn_s_setprio(1);
#pragma unroll
    for (int m = 0; m < 4; ++m)
#pragma unroll
      for (int n = 0; n < 4; ++n)
        acc[m][n] = __builtin_amdgcn_mfma_f32_16x16x32_bf16(
            av[m], bv[n], acc[m][n], 0, 0, 0);
    __builtin_amdgcn_s_setprio(0);
    __builtin_amdgcn_s_barrier();      // all reads of smem[t&1] done
    if (t < 14) STAGE(t & 1, t + 2);   // overwrite just-read buffer
  }
#undef STAGE

  const int blockRow = by * 128;
  const int blockCol = bx * 128;
  const int rowBase = blockRow + wm * 64;
  const int colBase = blockCol + wn * 64;

  // per-column inverse-norm factors (4 per thread)
  float rs2[4];
#pragma unroll
  for (int n = 0; n < 4; ++n) rs2[n] = rsqrtf(nsq2[colBase + n * 16 + l15]);

  // read-phase mapping: thread t handles chunk row (t>>3), 16 cols at (t&7)*16
  const int lr = tid >> 3;
  const int lcBase = (tid & 7) * 16;
  const int gRowRbase = blockRow + (lr >> 4) * 64 + (lr & 15);
  const int lrW = wm * 16 + l4 * 4;        // + reg
  const int lcW = wn * 64 + l15;           // + n*16

  float sumP = 0.f, sumT = 0.f;
#pragma unroll
  for (int m = 0; m < 4; ++m) {
    // coalesced pos/neg loads for this chunk (overlap with exp+ds_write)
    const float* pr = pos + (size_t)(gRowRbase + m * 16) * NROWS + blockCol + lcBase;
    const float* gr = neg + (size_t)(gRowRbase + m * 16) * NROWS + blockCol + lcBase;
    float4 pv[4], gv[4];
#pragma unroll
    for (int i = 0; i < 4; ++i) {
      pv[i] = *(const float4*)(pr + 4 * i);
      gv[i] = *(const float4*)(gr + 4 * i);
    }
    // compute s = exp(dot / (|z1||z2|) / tau), scatter into LDS chunk
#pragma unroll
    for (int reg = 0; reg < 4; ++reg) {
      float rs1 = rsqrtf(nsq1[rowBase + m * 16 + l4 * 4 + reg]);
#pragma unroll
      for (int n = 0; n < 4; ++n) {
        float s = __expf(acc[m][n][reg] * (rs1 * rs2[n]) * INV_TAU);
        sCh[(lrW + reg) * SROW + lcW + n * 16] = s;
      }
    }
    __syncthreads();
    // coalesced combine: s (LDS, linear) * pos/neg (regs)
#pragma unroll
    for (int i = 0; i < 4; ++i) {
      float4 s4 = *(const float4*)&sCh[lr * SROW + lcBase + 4 * i];
      sumP += s4.x * pv[i].x + s4.y * pv[i].y + s4.z * pv[i].z + s4.w * pv[i].w;
      sumT += s4.x * (pv[i].x + gv[i].x) + s4.y * (pv[i].y + gv[i].y) +
              s4.z * (pv[i].z + gv[i].z) + s4.w * (pv[i].w + gv[i].w);
    }
    __syncthreads();
  }

#pragma unroll
  for (int sft = 1; sft < 64; sft <<= 1) {
    sumP += __shfl_xor(sumP, sft, 64);
    sumT += __shfl_xor(sumT, sft, 64);
  }
  __shared__ float redP[4], redT[4];
  if (lane == 0) { redP[wid] = sumP; redT[wid] = sumT; }
  __syncthreads();
  if (tid == 0) {
    double tp = (double)redP[0] + redP[1] + redP[2] + redP[3];
    double tt = (double)redT[0] + redT[1] + redT[2] + redT[3];
    partials[2 * bid]     = tp;
    partials[2 * bid + 1] = tt;
  }
}

// ---------------------------------------------------------------------------
// Kernel 4: final reduce of 1024 partial pairs -> -log(sumP / sumT)
// ---------------------------------------------------------------------------
__global__ void finalize_kernel(const double* __restrict__ partials,
                                float* __restrict__ out) {
  __shared__ double sp[256], st[256];
  int t = threadIdx.x;
  double a = 0.0, b = 0.0;
  for (int i = t; i < 1024; i += 256) {
    a += partials[2 * i];
    b += partials[2 * i + 1];
  }
  sp[t] = a; st[t] = b;
  __syncthreads();
  for (int s = 128; s > 0; s >>= 1) {
    if (t < s) { sp[t] += sp[t + s]; st[t] += st[t + s]; }
    __syncthreads();
  }
  if (t == 0) out[0] = (float)(log(st[0]) - log(sp[0]));
}

// ---------------------------------------------------------------------------
extern "C" void kernel_launch(void* const* d_in, const int* in_sizes, int n_in,
                              void* d_out, int out_size, void* d_ws, size_t ws_size,
                              hipStream_t stream) {
  (void)in_sizes; (void)n_in; (void)out_size; (void)ws_size;
  const float* v1   = (const float*)d_in[0];
  const float* v2   = (const float*)d_in[1];
  const float* pos  = (const float*)d_in[2];
  const float* neg  = (const float*)d_in[3];
  const float* W    = (const float*)d_in[4];
  const float* bias = (const float*)d_in[5];

  char* ws = (char*)d_ws;
  unsigned short* z1b = (unsigned short*)(ws + 0);         // 4 MiB
  unsigned short* z2b = (unsigned short*)(ws + 4194304);   // 4 MiB
  unsigned short* v1b = (unsigned short*)(ws + 8388608);   // 4 MiB
  unsigned short* v2b = (unsigned short*)(ws + 12582912);  // 4 MiB
  unsigned short* Wb  = (unsigned short*)(ws + 16777216);  // 512 KiB
  float* nsq1         = (float*)(ws + 17301504);           // 16 KiB
  float* nsq2         = (float*)(ws + 17317888);           // 16 KiB
  double* partials    = (double*)(ws + 17334272);          // 16 KiB
  float* out = (float*)d_out;

  hipLaunchKernelGGL(convert_kernel, dim3(1024), dim3(256), 0, stream,
                     v1, v2, W, v1b, v2b, Wb, nsq1, nsq2);
  hipLaunchKernelGGL(proj_kernel, dim3(DDIM / 128, NROWS / 128, 2), dim3(256), 0, stream,
                     v1b, v2b, Wb, bias, z1b, z2b, nsq1, nsq2);
  hipLaunchKernelGGL(dots_kernel, dim3(1024), dim3(256), 0, stream,
                     z1b, z2b, nsq1, nsq2, pos, neg, partials);
  hipLaunchKernelGGL(finalize_kernel, dim3(1), dim3(256), 0, stream,
                     partials, out);
}

// Round 5
// 74.796 us; speedup vs baseline: 1.1459x; 1.0064x over previous
//
#include <hip/hip_runtime.h>
#include <hip/hip_bf16.h>
#include <math.h>

#define NROWS 4096
#define DDIM  512
#define INV_TAU 1.25f
#define SROW 132   // f32 stride of epilogue LDS chunk rows (bank spread)

typedef __attribute__((ext_vector_type(8))) short short8;
typedef __attribute__((ext_vector_type(4))) float f32x4;

__device__ inline void gload_lds16(const void* g, void* l) {
  __builtin_amdgcn_global_load_lds(
      (const __attribute__((address_space(1))) void*)g,
      (__attribute__((address_space(3))) void*)l, 16, 0, 0);
}

__device__ inline unsigned short f2bf(float f) {
  __hip_bfloat16 h = __float2bfloat16(f);
  return __builtin_bit_cast(unsigned short, h);
}
__device__ inline float bf2f(unsigned short u) {
  return __bfloat162float(__builtin_bit_cast(__hip_bfloat16, u));
}

// ---------------------------------------------------------------------------
// Kernel 1: f32 -> bf16 conversion for v1, v2, W ; zero the nsq accumulators.
// ---------------------------------------------------------------------------
__global__ void convert_kernel(const float* __restrict__ v1,
                               const float* __restrict__ v2,
                               const float* __restrict__ W,
                               unsigned short* __restrict__ v1b,
                               unsigned short* __restrict__ v2b,
                               unsigned short* __restrict__ Wb,
                               float* __restrict__ nsq1,
                               float* __restrict__ nsq2) {
  int idx = blockIdx.x * blockDim.x + threadIdx.x;
  if (idx < NROWS) { nsq1[idx] = 0.f; nsq2[idx] = 0.f; }
  const int TOTV = (NROWS * DDIM) / 4;
  const int TOTW = (DDIM * DDIM) / 4;
  const int total = 2 * TOTV + TOTW;
  const int stride = gridDim.x * blockDim.x;
  for (int i = idx; i < total; i += stride) {
    const float4* src; unsigned short* dst; int j;
    if (i < TOTV)            { src = (const float4*)v1; dst = v1b; j = i; }
    else if (i < 2 * TOTV)   { src = (const float4*)v2; dst = v2b; j = i - TOTV; }
    else                     { src = (const float4*)W;  dst = Wb;  j = i - 2 * TOTV; }
    float4 x = src[j];
    ushort4 o;
    o.x = f2bf(x.x); o.y = f2bf(x.y); o.z = f2bf(x.z); o.w = f2bf(x.w);
    *(ushort4*)&dst[j * 4] = o;
  }
}

// ---------------------------------------------------------------------------
// Kernel 2: projection GEMM  z = elu(v @ W^T + b), bf16 out, + row sum(z^2).
// grid: (512/128, 4096/128, 2)   block: 256
// ---------------------------------------------------------------------------
__global__ __launch_bounds__(256) void proj_kernel(
    const unsigned short* __restrict__ v1b, const unsigned short* __restrict__ v2b,
    const unsigned short* __restrict__ Wb,  const float* __restrict__ bias,
    unsigned short* __restrict__ z1b, unsigned short* __restrict__ z2b,
    float* __restrict__ nsq1, float* __restrict__ nsq2) {
  __shared__ __align__(16) unsigned short As[128 * 32];
  __shared__ __align__(16) unsigned short Bs[128 * 32];
  const int tid = threadIdx.x;
  const int wid = tid >> 6, lane = tid & 63;
  const int wm = wid >> 1, wn = wid & 1;
  const int l15 = lane & 15, l4 = lane >> 4;

  const int zsel = blockIdx.z;
  const unsigned short* Ag = (zsel ? v2b : v1b) + (size_t)blockIdx.y * 128 * DDIM;
  const unsigned short* Bg = Wb + (size_t)blockIdx.x * 128 * DDIM;
  unsigned short* Z = (zsel ? z2b : z1b);
  float* nsq = (zsel ? nsq2 : nsq1);

  f32x4 acc[4][4];
#pragma unroll
  for (int m = 0; m < 4; ++m)
#pragma unroll
    for (int n = 0; n < 4; ++n) acc[m][n] = (f32x4){0.f, 0.f, 0.f, 0.f};

  for (int kt = 0; kt < DDIM; kt += 32) {
#pragma unroll
    for (int i = 0; i < 2; ++i) {
      int off = i * 4096 + tid * 16;
      int row = off >> 6;
      int kb  = off & 63;
      gload_lds16((const char*)(Ag + row * DDIM + kt) + kb,
                  (char*)As + i * 4096 + wid * 1024);
      gload_lds16((const char*)(Bg + row * DDIM + kt) + kb,
                  (char*)Bs + i * 4096 + wid * 1024);
    }
    asm volatile("s_waitcnt vmcnt(0)" ::: "memory");
    __syncthreads();
    short8 av[4], bv[4];
#pragma unroll
    for (int m = 0; m < 4; ++m)
      av[m] = *(const short8*)&As[(wm * 64 + m * 16 + l15) * 32 + l4 * 8];
#pragma unroll
    for (int n = 0; n < 4; ++n)
      bv[n] = *(const short8*)&Bs[(wn * 64 + n * 16 + l15) * 32 + l4 * 8];
#pragma unroll
    for (int m = 0; m < 4; ++m)
#pragma unroll
      for (int n = 0; n < 4; ++n)
        acc[m][n] = __builtin_amdgcn_mfma_f32_16x16x32_bf16(
            av[m], bv[n], acc[m][n], 0, 0, 0);
    __syncthreads();
  }

  const int rowBase = blockIdx.y * 128 + wm * 64;
  const int colBase = blockIdx.x * 128 + wn * 64;
  float bcol[4];
#pragma unroll
  for (int n = 0; n < 4; ++n) bcol[n] = bias[colBase + n * 16 + l15];
#pragma unroll
  for (int m = 0; m < 4; ++m) {
#pragma unroll
    for (int reg = 0; reg < 4; ++reg) {
      int gRow = rowBase + m * 16 + l4 * 4 + reg;
      float rs = 0.f;
#pragma unroll
      for (int n = 0; n < 4; ++n) {
        int gCol = colBase + n * 16 + l15;
        float y = acc[m][n][reg] + bcol[n];
        float zv = (y > 0.f) ? y : expm1f(y);
        unsigned short zb = f2bf(zv);
        Z[(size_t)gRow * DDIM + gCol] = zb;
        float zf = bf2f(zb);
        rs += zf * zf;
      }
      rs += __shfl_xor(rs, 1, 64);
      rs += __shfl_xor(rs, 2, 64);
      rs += __shfl_xor(rs, 4, 64);
      rs += __shfl_xor(rs, 8, 64);
      if (l15 == 0) atomicAdd(&nsq[gRow], rs);
    }
  }
}

// ---------------------------------------------------------------------------
// Kernel 3: dots = z1 @ z2^T fused epilogue.  Counted-vmcnt 2-buffer pipeline
// + T2 granule swizzle: LDS granule (row,G) holds global granule G^((row>>1)&3)
// (pre-swizzled global source, linear LDS dest); reads apply the same
// involution -> ds_read_b128 drops from 8-way to 2-way bank conflict (free).
// grid: 1024 linear  block: 256.
// ---------------------------------------------------------------------------
__global__ __launch_bounds__(256, 4) void dots_kernel(
    const unsigned short* __restrict__ z1b, const unsigned short* __restrict__ z2b,
    const float* __restrict__ nsq1, const float* __restrict__ nsq2,
    const float* __restrict__ pos, const float* __restrict__ neg,
    double* __restrict__ partials) {
  __shared__ __align__(16) char smem[2][16384];
  float* sCh = (float*)smem;   // 32 x SROW f32 = 16.9 KB

  const int tid = threadIdx.x;
  const int wid = tid >> 6, lane = tid & 63;
  const int wm = wid >> 1, wn = wid & 1;
  const int l15 = lane & 15, l4 = lane >> 4;

  const int bid = blockIdx.x;
  const int by = bid >> 5, bx = bid & 31;   // linear order (L3-friendly)

  const unsigned short* Ag = z1b + (size_t)by * 128 * DDIM;
  const unsigned short* Bg = z2b + (size_t)bx * 128 * DDIM;

  f32x4 acc[4][4];
#pragma unroll
  for (int m = 0; m < 4; ++m)
#pragma unroll
    for (int n = 0; n < 4; ++n) acc[m][n] = (f32x4){0.f, 0.f, 0.f, 0.f};

  // stage K-tile t into smem[buf]; global source granule pre-swizzled so the
  // (linear-dest) LDS tile ends up XOR-swizzled: slot (row,G) <- global G^s(row)
#define STAGE(buf, t)                                                          \
  {                                                                            \
    _Pragma("unroll")                                                          \
    for (int i = 0; i < 2; ++i) {                                              \
      int off = i * 4096 + tid * 16;                                           \
      int row = off >> 6;              /* tile row 0..127 */                   \
      int gsw = ((off >> 4) & 3) ^ ((row >> 1) & 3);                           \
      gload_lds16((const char*)Ag + row * 1024 + (t) * 64 + gsw * 16,          \
                  smem[buf] + i * 4096 + wid * 1024);                          \
      gload_lds16((const char*)Bg + row * 1024 + (t) * 64 + gsw * 16,          \
                  smem[buf] + 8192 + i * 4096 + wid * 1024);                   \
    }                                                                          \
  }

  // prologue: tiles 0 and 1 in flight (8 outstanding loads)
  STAGE(0, 0);
  STAGE(1, 1);

  const int aswz = (l4 ^ ((l15 >> 1) & 3)) * 8;   // swizzled granule for reads

#pragma unroll
  for (int t = 0; t < 16; ++t) {
    // wait tile t (oldest 4 loads); tile t+1's 4 stay in flight
    if (t < 15) asm volatile("s_waitcnt vmcnt(4)" ::: "memory");
    else        asm volatile("s_waitcnt vmcnt(0)" ::: "memory");
    __builtin_amdgcn_s_barrier();      // raw: no implicit vmcnt drain
    const unsigned short* As = (const unsigned short*)smem[t & 1];
    const unsigned short* Bs = (const unsigned short*)(smem[t & 1] + 8192);
    short8 av[4], bv[4];
#pragma unroll
    for (int m = 0; m < 4; ++m)
      av[m] = *(const short8*)&As[(wm * 64 + m * 16 + l15) * 32 + aswz];
#pragma unroll
    for (int n = 0; n < 4; ++n)
      bv[n] = *(const short8*)&Bs[(wn * 64 + n * 16 + l15) * 32 + aswz];
#pragma unroll
    for (int m = 0; m < 4; ++m)
#pragma unroll
      for (int n = 0; n < 4; ++n)
        acc[m][n] = __builtin_amdgcn_mfma_f32_16x16x32_bf16(
            av[m], bv[n], acc[m][n], 0, 0, 0);
    __builtin_amdgcn_s_barrier();      // all reads of smem[t&1] done
    if (t < 14) STAGE(t & 1, t + 2);   // overwrite just-read buffer
  }
#undef STAGE

  const int blockRow = by * 128;
  const int blockCol = bx * 128;
  const int rowBase = blockRow + wm * 64;
  const int colBase = blockCol + wn * 64;

  float rs2[4];
#pragma unroll
  for (int n = 0; n < 4; ++n) rs2[n] = rsqrtf(nsq2[colBase + n * 16 + l15]);

  // read-phase mapping: thread t handles chunk row (t>>3), 16 cols at (t&7)*16
  const int lr = tid >> 3;
  const int lcBase = (tid & 7) * 16;
  const int gRowRbase = blockRow + (lr >> 4) * 64 + (lr & 15);
  const int lrW = wm * 16 + l4 * 4;        // + reg
  const int lcW = wn * 64 + l15;           // + n*16

  float sumP = 0.f, sumT = 0.f;
#pragma unroll
  for (int m = 0; m < 4; ++m) {
    // coalesced pos/neg loads for this chunk (issued first; exp hides latency)
    const float* pr = pos + (size_t)(gRowRbase + m * 16) * NROWS + blockCol + lcBase;
    const float* gr = neg + (size_t)(gRowRbase + m * 16) * NROWS + blockCol + lcBase;
    float4 pv[4], gv[4];
#pragma unroll
    for (int i = 0; i < 4; ++i) {
      pv[i] = *(const float4*)(pr + 4 * i);
      gv[i] = *(const float4*)(gr + 4 * i);
    }
    // compute s = exp(dot / (|z1||z2|) / tau), scatter into LDS chunk
#pragma unroll
    for (int reg = 0; reg < 4; ++reg) {
      float rs1 = rsqrtf(nsq1[rowBase + m * 16 + l4 * 4 + reg]);
#pragma unroll
      for (int n = 0; n < 4; ++n) {
        float s = __expf(acc[m][n][reg] * (rs1 * rs2[n]) * INV_TAU);
        sCh[(lrW + reg) * SROW + lcW + n * 16] = s;
      }
    }
    __syncthreads();
    // coalesced combine: s (LDS, linear) * pos/neg (regs)
#pragma unroll
    for (int i = 0; i < 4; ++i) {
      float4 s4 = *(const float4*)&sCh[lr * SROW + lcBase + 4 * i];
      sumP += s4.x * pv[i].x + s4.y * pv[i].y + s4.z * pv[i].z + s4.w * pv[i].w;
      sumT += s4.x * (pv[i].x + gv[i].x) + s4.y * (pv[i].y + gv[i].y) +
              s4.z * (pv[i].z + gv[i].z) + s4.w * (pv[i].w + gv[i].w);
    }
    __syncthreads();
  }

#pragma unroll
  for (int sft = 1; sft < 64; sft <<= 1) {
    sumP += __shfl_xor(sumP, sft, 64);
    sumT += __shfl_xor(sumT, sft, 64);
  }
  __shared__ float redP[4], redT[4];
  if (lane == 0) { redP[wid] = sumP; redT[wid] = sumT; }
  __syncthreads();
  if (tid == 0) {
    double tp = (double)redP[0] + redP[1] + redP[2] + redP[3];
    double tt = (double)redT[0] + redT[1] + redT[2] + redT[3];
    partials[2 * bid]     = tp;
    partials[2 * bid + 1] = tt;
  }
}

// ---------------------------------------------------------------------------
// Kernel 4: final reduce of 1024 partial pairs -> -log(sumP / sumT)
// ---------------------------------------------------------------------------
__global__ void finalize_kernel(const double* __restrict__ partials,
                                float* __restrict__ out) {
  __shared__ double sp[256], st[256];
  int t = threadIdx.x;
  double a = 0.0, b = 0.0;
  for (int i = t; i < 1024; i += 256) {
    a += partials[2 * i];
    b += partials[2 * i + 1];
  }
  sp[t] = a; st[t] = b;
  __syncthreads();
  for (int s = 128; s > 0; s >>= 1) {
    if (t < s) { sp[t] += sp[t + s]; st[t] += st[t + s]; }
    __syncthreads();
  }
  if (t == 0) out[0] = (float)(log(st[0]) - log(sp[0]));
}

// ---------------------------------------------------------------------------
extern "C" void kernel_launch(void* const* d_in, const int* in_sizes, int n_in,
                              void* d_out, int out_size, void* d_ws, size_t ws_size,
                              hipStream_t stream) {
  (void)in_sizes; (void)n_in; (void)out_size; (void)ws_size;
  const float* v1   = (const float*)d_in[0];
  const float* v2   = (const float*)d_in[1];
  const float* pos  = (const float*)d_in[2];
  const float* neg  = (const float*)d_in[3];
  const float* W    = (const float*)d_in[4];
  const float* bias = (const float*)d_in[5];

  char* ws = (char*)d_ws;
  unsigned short* z1b = (unsigned short*)(ws + 0);         // 4 MiB
  unsigned short* z2b = (unsigned short*)(ws + 4194304);   // 4 MiB
  unsigned short* v1b = (unsigned short*)(ws + 8388608);   // 4 MiB
  unsigned short* v2b = (unsigned short*)(ws + 12582912);  // 4 MiB
  unsigned short* Wb  = (unsigned short*)(ws + 16777216);  // 512 KiB
  float* nsq1         = (float*)(ws + 17301504);           // 16 KiB
  float* nsq2         = (float*)(ws + 17317888);           // 16 KiB
  double* partials    = (double*)(ws + 17334272);          // 16 KiB
  float* out = (float*)d_out;

  hipLaunchKernelGGL(convert_kernel, dim3(1024), dim3(256), 0, stream,
                     v1, v2, W, v1b, v2b, Wb, nsq1, nsq2);
  hipLaunchKernelGGL(proj_kernel, dim3(DDIM / 128, NROWS / 128, 2), dim3(256), 0, stream,
                     v1b, v2b, Wb, bias, z1b, z2b, nsq1, nsq2);
  hipLaunchKernelGGL(dots_kernel, dim3(1024), dim3(256), 0, stream,
                     z1b, z2b, nsq1, nsq2, pos, neg, partials);
  hipLaunchKernelGGL(finalize_kernel, dim3(1), dim3(256), 0, stream,
                     partials, out);
}

// Round 6
// 70.190 us; speedup vs baseline: 1.2211x; 1.0656x over previous
//
#include <hip/hip_runtime.h>
#include <hip/hip_bf16.h>
#include <math.h>

#define NROWS 4096
#define DDIM  512
#define INV_TAU 1.25f
#define SROW 260   // f32 stride of epilogue LDS chunk rows (bank spread)

typedef __attribute__((ext_vector_type(8))) short short8;
typedef __attribute__((ext_vector_type(4))) float f32x4;

__device__ inline void gload_lds16(const void* g, void* l) {
  __builtin_amdgcn_global_load_lds(
      (const __attribute__((address_space(1))) void*)g,
      (__attribute__((address_space(3))) void*)l, 16, 0, 0);
}

__device__ inline unsigned short f2bf(float f) {
  __hip_bfloat16 h = __float2bfloat16(f);
  return __builtin_bit_cast(unsigned short, h);
}
__device__ inline float bf2f(unsigned short u) {
  return __bfloat162float(__builtin_bit_cast(__hip_bfloat16, u));
}

// ---------------------------------------------------------------------------
// Kernel 1: f32 -> bf16 conversion for v1, v2, W ; zero the nsq accumulators.
// ---------------------------------------------------------------------------
__global__ void convert_kernel(const float* __restrict__ v1,
                               const float* __restrict__ v2,
                               const float* __restrict__ W,
                               unsigned short* __restrict__ v1b,
                               unsigned short* __restrict__ v2b,
                               unsigned short* __restrict__ Wb,
                               float* __restrict__ nsq1,
                               float* __restrict__ nsq2) {
  int idx = blockIdx.x * blockDim.x + threadIdx.x;
  if (idx < NROWS) { nsq1[idx] = 0.f; nsq2[idx] = 0.f; }
  const int TOTV = (NROWS * DDIM) / 4;
  const int TOTW = (DDIM * DDIM) / 4;
  const int total = 2 * TOTV + TOTW;
  const int stride = gridDim.x * blockDim.x;
  for (int i = idx; i < total; i += stride) {
    const float4* src; unsigned short* dst; int j;
    if (i < TOTV)            { src = (const float4*)v1; dst = v1b; j = i; }
    else if (i < 2 * TOTV)   { src = (const float4*)v2; dst = v2b; j = i - TOTV; }
    else                     { src = (const float4*)W;  dst = Wb;  j = i - 2 * TOTV; }
    float4 x = src[j];
    ushort4 o;
    o.x = f2bf(x.x); o.y = f2bf(x.y); o.z = f2bf(x.z); o.w = f2bf(x.w);
    *(ushort4*)&dst[j * 4] = o;
  }
}

// ---------------------------------------------------------------------------
// Kernel 2: projection GEMM  z = elu(v @ W^T + b), bf16 out, + row sum(z^2).
// grid: (512/128, 4096/128, 2)   block: 256   (~2 us; not the bottleneck)
// ---------------------------------------------------------------------------
__global__ __launch_bounds__(256) void proj_kernel(
    const unsigned short* __restrict__ v1b, const unsigned short* __restrict__ v2b,
    const unsigned short* __restrict__ Wb,  const float* __restrict__ bias,
    unsigned short* __restrict__ z1b, unsigned short* __restrict__ z2b,
    float* __restrict__ nsq1, float* __restrict__ nsq2) {
  __shared__ __align__(16) unsigned short As[128 * 32];
  __shared__ __align__(16) unsigned short Bs[128 * 32];
  const int tid = threadIdx.x;
  const int wid = tid >> 6, lane = tid & 63;
  const int wm = wid >> 1, wn = wid & 1;
  const int l15 = lane & 15, l4 = lane >> 4;

  const int zsel = blockIdx.z;
  const unsigned short* Ag = (zsel ? v2b : v1b) + (size_t)blockIdx.y * 128 * DDIM;
  const unsigned short* Bg = Wb + (size_t)blockIdx.x * 128 * DDIM;
  unsigned short* Z = (zsel ? z2b : z1b);
  float* nsq = (zsel ? nsq2 : nsq1);

  f32x4 acc[4][4];
#pragma unroll
  for (int m = 0; m < 4; ++m)
#pragma unroll
    for (int n = 0; n < 4; ++n) acc[m][n] = (f32x4){0.f, 0.f, 0.f, 0.f};

  for (int kt = 0; kt < DDIM; kt += 32) {
#pragma unroll
    for (int i = 0; i < 2; ++i) {
      int off = i * 4096 + tid * 16;
      int row = off >> 6;
      int kb  = off & 63;
      gload_lds16((const char*)(Ag + row * DDIM + kt) + kb,
                  (char*)As + i * 4096 + wid * 1024);
      gload_lds16((const char*)(Bg + row * DDIM + kt) + kb,
                  (char*)Bs + i * 4096 + wid * 1024);
    }
    asm volatile("s_waitcnt vmcnt(0)" ::: "memory");
    __syncthreads();
    short8 av[4], bv[4];
#pragma unroll
    for (int m = 0; m < 4; ++m)
      av[m] = *(const short8*)&As[(wm * 64 + m * 16 + l15) * 32 + l4 * 8];
#pragma unroll
    for (int n = 0; n < 4; ++n)
      bv[n] = *(const short8*)&Bs[(wn * 64 + n * 16 + l15) * 32 + l4 * 8];
#pragma unroll
    for (int m = 0; m < 4; ++m)
#pragma unroll
      for (int n = 0; n < 4; ++n)
        acc[m][n] = __builtin_amdgcn_mfma_f32_16x16x32_bf16(
            av[m], bv[n], acc[m][n], 0, 0, 0);
    __syncthreads();
  }

  const int rowBase = blockIdx.y * 128 + wm * 64;
  const int colBase = blockIdx.x * 128 + wn * 64;
  float bcol[4];
#pragma unroll
  for (int n = 0; n < 4; ++n) bcol[n] = bias[colBase + n * 16 + l15];
#pragma unroll
  for (int m = 0; m < 4; ++m) {
#pragma unroll
    for (int reg = 0; reg < 4; ++reg) {
      int gRow = rowBase + m * 16 + l4 * 4 + reg;
      float rs = 0.f;
#pragma unroll
      for (int n = 0; n < 4; ++n) {
        int gCol = colBase + n * 16 + l15;
        float y = acc[m][n][reg] + bcol[n];
        float zv = (y > 0.f) ? y : expm1f(y);
        unsigned short zb = f2bf(zv);
        Z[(size_t)gRow * DDIM + gCol] = zb;
        float zf = bf2f(zb);
        rs += zf * zf;
      }
      rs += __shfl_xor(rs, 1, 64);
      rs += __shfl_xor(rs, 2, 64);
      rs += __shfl_xor(rs, 4, 64);
      rs += __shfl_xor(rs, 8, 64);
      if (l15 == 0) atomicAdd(&nsq[gRow], rs);
    }
  }
}

// ---------------------------------------------------------------------------
// Kernel 3: dots = z1 @ z2^T fused epilogue.  256x256 tile, 8 waves (2x4),
// BK=32, counted-vmcnt 2-buffer pipeline, granule swizzle (conflict-free),
// 4x8 rectangular XCD chunking (per-XCD working set 3MB -> L2-resident z).
// grid: 256 linear  block: 512.
// ---------------------------------------------------------------------------
__global__ __launch_bounds__(512, 1) void dots_kernel(
    const unsigned short* __restrict__ z1b, const unsigned short* __restrict__ z2b,
    const float* __restrict__ nsq1, const float* __restrict__ nsq2,
    const float* __restrict__ pos, const float* __restrict__ neg,
    double* __restrict__ partials) {
  // two 32KB staging buffers (each: A 16KB | B 16KB); epilogue reuses as sCh.
  __shared__ __align__(16) char smem[2][32768];
  float* sCh = (float*)smem;   // 32 x SROW f32 = 33.3 KB

  const int tid = threadIdx.x;
  const int wid = tid >> 6, lane = tid & 63;
  const int wm = wid >> 2, wn = wid & 3;       // 2 x 4 wave grid
  const int l15 = lane & 15, l4 = lane >> 4;

  // XCD chunking: XCD k (= bid%8, round-robin dispatch) gets contiguous swz
  // range [k*32, k*32+32) mapped to a 4(by) x 8(bx) rectangle of tiles.
  const int bid = blockIdx.x;
  const int swz = (bid & 7) * 32 + (bid >> 3);
  const int S = swz >> 5, s5 = swz & 31;
  const int by = (S >> 1) * 4 + (s5 >> 3);
  const int bx = (S & 1) * 8 + (s5 & 7);

  const unsigned short* Ag = z1b + (size_t)by * 256 * DDIM;
  const unsigned short* Bg = z2b + (size_t)bx * 256 * DDIM;

  f32x4 acc[8][4];
#pragma unroll
  for (int m = 0; m < 8; ++m)
#pragma unroll
    for (int n = 0; n < 4; ++n) acc[m][n] = (f32x4){0.f, 0.f, 0.f, 0.f};

  // stage K-tile t into smem[buf]; global source granule pre-swizzled so the
  // (linear-dest) LDS tile is XOR-swizzled: slot (row,G) <- global G^((row>>1)&3)
  // 4 gload_lds per thread (2 A rounds + 2 B rounds), 32KB per tile-pair.
#define STAGE(buf, t)                                                          \
  {                                                                            \
    _Pragma("unroll")                                                          \
    for (int i = 0; i < 2; ++i) {                                              \
      int off = i * 8192 + tid * 16;                                           \
      int row = off >> 6;              /* tile row 0..255 */                   \
      int gsw = ((off >> 4) & 3) ^ ((row >> 1) & 3);                           \
      gload_lds16((const char*)Ag + row * 1024 + (t) * 64 + gsw * 16,          \
                  smem[buf] + i * 8192 + wid * 1024);                          \
      gload_lds16((const char*)Bg + row * 1024 + (t) * 64 + gsw * 16,          \
                  smem[buf] + 16384 + i * 8192 + wid * 1024);                  \
    }                                                                          \
  }

  // prologue: tiles 0 and 1 in flight (8 outstanding loads per wave)
  STAGE(0, 0);
  STAGE(1, 1);

  const int aswz = (l4 ^ ((l15 >> 1) & 3)) * 8;   // swizzled granule for reads

#pragma unroll
  for (int t = 0; t < 16; ++t) {
    // wait tile t (oldest 4 loads); tile t+1's 4 stay in flight
    if (t < 15) asm volatile("s_waitcnt vmcnt(4)" ::: "memory");
    else        asm volatile("s_waitcnt vmcnt(0)" ::: "memory");
    __builtin_amdgcn_s_barrier();      // raw: no implicit vmcnt drain
    const unsigned short* As = (const unsigned short*)smem[t & 1];
    const unsigned short* Bs = (const unsigned short*)(smem[t & 1] + 16384);
    short8 av[8], bv[4];
#pragma unroll
    for (int m = 0; m < 8; ++m)
      av[m] = *(const short8*)&As[(wm * 128 + m * 16 + l15) * 32 + aswz];
#pragma unroll
    for (int n = 0; n < 4; ++n)
      bv[n] = *(const short8*)&Bs[(wn * 64 + n * 16 + l15) * 32 + aswz];
#pragma unroll
    for (int m = 0; m < 8; ++m)
#pragma unroll
      for (int n = 0; n < 4; ++n)
        acc[m][n] = __builtin_amdgcn_mfma_f32_16x16x32_bf16(
            av[m], bv[n], acc[m][n], 0, 0, 0);
    __builtin_amdgcn_s_barrier();      // all reads of smem[t&1] done
    if (t < 14) STAGE(t & 1, t + 2);   // overwrite just-read buffer
  }
#undef STAGE

  const int blockRow = by * 256;
  const int blockCol = bx * 256;

  // per-column inverse-norm factors (4 per thread)
  float rs2[4];
#pragma unroll
  for (int n = 0; n < 4; ++n)
    rs2[n] = rsqrtf(nsq2[blockCol + wn * 64 + n * 16 + l15]);

  // epilogue: 8 chunks of 32 rows x 256 cols.
  // write mapping: LDS row = wm*16 + l4*4 + reg, col = wn*64 + n*16 + l15
  // read mapping: thread t -> LDS row t>>4, 16 cols at (t&15)*16
  const int lr = tid >> 4;
  const int lcBase = (tid & 15) * 16;
  const int lrW = wm * 16 + l4 * 4;        // + reg
  const int lcW = wn * 64 + l15;           // + n*16

  float sumP = 0.f, sumT = 0.f;
#pragma unroll
  for (int m = 0; m < 8; ++m) {
    // coalesced pos/neg loads for this chunk (issued first; exp hides latency)
    const int gRowR = blockRow + (lr >> 4) * 128 + m * 16 + (lr & 15);
    const float* pr = pos + (size_t)gRowR * NROWS + blockCol + lcBase;
    const float* gr = neg + (size_t)gRowR * NROWS + blockCol + lcBase;
    float4 pv[4], gv[4];
#pragma unroll
    for (int i = 0; i < 4; ++i) {
      pv[i] = *(const float4*)(pr + 4 * i);
      gv[i] = *(const float4*)(gr + 4 * i);
    }
    // compute s = exp(dot / (|z1||z2|) / tau), scatter into LDS chunk
#pragma unroll
    for (int reg = 0; reg < 4; ++reg) {
      float rs1 = rsqrtf(nsq1[blockRow + wm * 128 + m * 16 + l4 * 4 + reg]);
#pragma unroll
      for (int n = 0; n < 4; ++n) {
        float ss = __expf(acc[m][n][reg] * (rs1 * rs2[n]) * INV_TAU);
        sCh[(lrW + reg) * SROW + lcW + n * 16] = ss;
      }
    }
    __syncthreads();
    // coalesced combine: s (LDS, linear) * pos/neg (regs)
#pragma unroll
    for (int i = 0; i < 4; ++i) {
      float4 s4 = *(const float4*)&sCh[lr * SROW + lcBase + 4 * i];
      sumP += s4.x * pv[i].x + s4.y * pv[i].y + s4.z * pv[i].z + s4.w * pv[i].w;
      sumT += s4.x * (pv[i].x + gv[i].x) + s4.y * (pv[i].y + gv[i].y) +
              s4.z * (pv[i].z + gv[i].z) + s4.w * (pv[i].w + gv[i].w);
    }
    __syncthreads();
  }

#pragma unroll
  for (int sft = 1; sft < 64; sft <<= 1) {
    sumP += __shfl_xor(sumP, sft, 64);
    sumT += __shfl_xor(sumT, sft, 64);
  }
  __shared__ float redP[8], redT[8];
  if (lane == 0) { redP[wid] = sumP; redT[wid] = sumT; }
  __syncthreads();
  if (tid == 0) {
    double tp = 0.0, tt = 0.0;
#pragma unroll
    for (int w = 0; w < 8; ++w) { tp += redP[w]; tt += redT[w]; }
    partials[2 * bid]     = tp;
    partials[2 * bid + 1] = tt;
  }
}

// ---------------------------------------------------------------------------
// Kernel 4: final reduce of 256 partial pairs -> -log(sumP / sumT)
// ---------------------------------------------------------------------------
__global__ void finalize_kernel(const double* __restrict__ partials,
                                float* __restrict__ out) {
  __shared__ double sp[256], st[256];
  int t = threadIdx.x;
  sp[t] = partials[2 * t];
  st[t] = partials[2 * t + 1];
  __syncthreads();
  for (int s = 128; s > 0; s >>= 1) {
    if (t < s) { sp[t] += sp[t + s]; st[t] += st[t + s]; }
    __syncthreads();
  }
  if (t == 0) out[0] = (float)(log(st[0]) - log(sp[0]));
}

// ---------------------------------------------------------------------------
extern "C" void kernel_launch(void* const* d_in, const int* in_sizes, int n_in,
                              void* d_out, int out_size, void* d_ws, size_t ws_size,
                              hipStream_t stream) {
  (void)in_sizes; (void)n_in; (void)out_size; (void)ws_size;
  const float* v1   = (const float*)d_in[0];
  const float* v2   = (const float*)d_in[1];
  const float* pos  = (const float*)d_in[2];
  const float* neg  = (const float*)d_in[3];
  const float* W    = (const float*)d_in[4];
  const float* bias = (const float*)d_in[5];

  char* ws = (char*)d_ws;
  unsigned short* z1b = (unsigned short*)(ws + 0);         // 4 MiB
  unsigned short* z2b = (unsigned short*)(ws + 4194304);   // 4 MiB
  unsigned short* v1b = (unsigned short*)(ws + 8388608);   // 4 MiB
  unsigned short* v2b = (unsigned short*)(ws + 12582912);  // 4 MiB
  unsigned short* Wb  = (unsigned short*)(ws + 16777216);  // 512 KiB
  float* nsq1         = (float*)(ws + 17301504);           // 16 KiB
  float* nsq2         = (float*)(ws + 17317888);           // 16 KiB
  double* partials    = (double*)(ws + 17334272);          // 16 KiB
  float* out = (float*)d_out;

  hipLaunchKernelGGL(convert_kernel, dim3(1024), dim3(256), 0, stream,
                     v1, v2, W, v1b, v2b, Wb, nsq1, nsq2);
  hipLaunchKernelGGL(proj_kernel, dim3(DDIM / 128, NROWS / 128, 2), dim3(256), 0, stream,
                     v1b, v2b, Wb, bias, z1b, z2b, nsq1, nsq2);
  hipLaunchKernelGGL(dots_kernel, dim3(256), dim3(512), 0, stream,
                     z1b, z2b, nsq1, nsq2, pos, neg, partials);
  hipLaunchKernelGGL(finalize_kernel, dim3(1), dim3(256), 0, stream,
                     partials, out);
}